// Round 6
// baseline (2195.918 us; speedup 1.0000x reference)
//
#include <hip/hip_runtime.h>

// ---------------- problem constants ----------------
#define BB   32
#define SS   512
#define DD   256
#define HH   8
#define HDIM 64
#define NLAYER 5
#define FFD  1024
#define OUTD 4096
#define QN   512            // H*HD
#define BS   (BB*SS)        // 16384 tokens

typedef short bf16x8 __attribute__((ext_vector_type(8)));
typedef float f32x4  __attribute__((ext_vector_type(4)));

__device__ __forceinline__ ushort f2bf(float f) {
    union { float f; unsigned u; } c; c.f = f;
    unsigned u = c.u;
    return (ushort)((u + 0x7fffu + ((u >> 16) & 1u)) >> 16);  // RNE
}
__device__ __forceinline__ float bf2f(unsigned b) {
    union { unsigned u; float f; } c; c.u = b << 16;
    return c.f;
}

// ---------------- embedding + positional encoding ----------------
__global__ __launch_bounds__(256) void embed_pe_kernel(
        const int* __restrict__ x, const float* __restrict__ emb,
        float* __restrict__ h, ushort* __restrict__ hb) {
    int t = blockIdx.x;
    int d = threadIdx.x;
    int pos = t % SS;
    int tok = x[t];
    float e = emb[(size_t)tok * DD + d];
    float expo = -(float)(d & ~1) / (float)DD;
    float ang = (float)pos * __expf(expo * 9.210340371976184f);  // 10000^expo
    float pe = (d & 1) ? __cosf(ang) : __sinf(ang);
    float val = e + pe;
    h[(size_t)t * DD + d] = val;
    hb[(size_t)t * DD + d] = f2bf(val);
}

// ---------------- weight convert + transpose: W[K][N] f32 -> Wt[N][K] bf16 ----
__global__ __launch_bounds__(256) void convw_kernel(
        const float* __restrict__ W, ushort* __restrict__ Wt, int K, int N) {
    __shared__ float t[32][33];
    const int tid = threadIdx.x;
    const int tx = tid & 31, ty = tid >> 5;   // 32 x 8
    const int n0 = blockIdx.x * 32, k0 = blockIdx.y * 32;
#pragma unroll
    for (int i = 0; i < 4; ++i)
        t[ty + i * 8][tx] = W[(size_t)(k0 + ty + i * 8) * N + n0 + tx];
    __syncthreads();
#pragma unroll
    for (int i = 0; i < 4; ++i)
        Wt[(size_t)(n0 + ty + i * 8) * K + k0 + tx] = f2bf(t[tx][ty + i * 8]);
}

// ---------------- MFMA bf16 GEMM (128x128 tile, reg-prefetch pipeline) -------
// C[M][N] = A[M][K] * Wt[N][K]^T + bias.  4 waves (2x2 of 64x64), BK=32.
template<bool RELU, bool OBF>
__global__ __launch_bounds__(256) void gemm_mfma_kernel(
        const ushort* __restrict__ A, const ushort* __restrict__ Bt,
        const float* __restrict__ bias, void* __restrict__ Cout,
        int M, int N, int K) {
    __shared__ ushort sA[128 * 32];
    __shared__ ushort sB[128 * 32];

    const int tid  = threadIdx.x;
    const int lane = tid & 63;
    const int wave = tid >> 6;
    const int wr   = wave >> 1;
    const int wc   = wave & 1;
    const int fr   = lane & 15;
    const int fq   = lane >> 4;
    const int m0 = blockIdx.y * 128;
    const int n0 = blockIdx.x * 128;

    const int strow = tid >> 2;               // 0..63 (it adds 64)
    const int stg   = tid & 3;
    const int stgs  = stg ^ ((strow >> 1) & 3);  // same for row and row+64

    f32x4 acc[4][4];
#pragma unroll
    for (int mi = 0; mi < 4; ++mi)
#pragma unroll
        for (int ni = 0; ni < 4; ++ni)
            acc[mi][ni] = (f32x4){0.0f, 0.0f, 0.0f, 0.0f};

    uint4 apre[2], bpre[2];
#pragma unroll
    for (int it = 0; it < 2; ++it) {
        apre[it] = *reinterpret_cast<const uint4*>(
            A + (size_t)(m0 + strow + it * 64) * K + stg * 8);
        bpre[it] = *reinterpret_cast<const uint4*>(
            Bt + (size_t)(n0 + strow + it * 64) * K + stg * 8);
    }

    for (int k0 = 0; k0 < K; k0 += 32) {
#pragma unroll
        for (int it = 0; it < 2; ++it) {
            *reinterpret_cast<uint4*>(&sA[(strow + it * 64) * 32 + stgs * 8]) = apre[it];
            *reinterpret_cast<uint4*>(&sB[(strow + it * 64) * 32 + stgs * 8]) = bpre[it];
        }
        __syncthreads();
        if (k0 + 32 < K) {
#pragma unroll
            for (int it = 0; it < 2; ++it) {
                apre[it] = *reinterpret_cast<const uint4*>(
                    A + (size_t)(m0 + strow + it * 64) * K + k0 + 32 + stg * 8);
                bpre[it] = *reinterpret_cast<const uint4*>(
                    Bt + (size_t)(n0 + strow + it * 64) * K + k0 + 32 + stg * 8);
            }
        }

        bf16x8 af[4], bfr[4];
#pragma unroll
        for (int mi = 0; mi < 4; ++mi) {
            const int row = wr * 64 + mi * 16 + fr;
            const int gs  = fq ^ ((row >> 1) & 3);
            af[mi] = *reinterpret_cast<const bf16x8*>(&sA[row * 32 + gs * 8]);
        }
#pragma unroll
        for (int ni = 0; ni < 4; ++ni) {
            const int row = wc * 64 + ni * 16 + fr;
            const int gs  = fq ^ ((row >> 1) & 3);
            bfr[ni] = *reinterpret_cast<const bf16x8*>(&sB[row * 32 + gs * 8]);
        }
#pragma unroll
        for (int mi = 0; mi < 4; ++mi)
#pragma unroll
            for (int ni = 0; ni < 4; ++ni)
                acc[mi][ni] = __builtin_amdgcn_mfma_f32_16x16x32_bf16(
                    af[mi], bfr[ni], acc[mi][ni], 0, 0, 0);
        __syncthreads();
    }

#pragma unroll
    for (int ni = 0; ni < 4; ++ni) {
        const int col = n0 + wc * 64 + ni * 16 + fr;
        const float bv = bias[col];
#pragma unroll
        for (int mi = 0; mi < 4; ++mi) {
#pragma unroll
            for (int r = 0; r < 4; ++r) {
                const int row = m0 + wr * 64 + mi * 16 + fq * 4 + r;
                float v = acc[mi][ni][r] + bv;
                if (RELU) v = fmaxf(v, 0.0f);
                if (OBF)
                    ((ushort*)Cout)[(size_t)row * N + col] = f2bf(v);
                else
                    ((float*)Cout)[(size_t)row * N + col] = v;
            }
        }
    }
}

// ---------------- fused QKV GEMM ----------------
// A[BS][256] bf16, Bt = wqkv_t[1536][256] bf16 (rows 0..511 wq^T, 512..1023
// wk^T, 1024..1535 wv^T). q,k written row-major [BS][512]; v written
// TRANSPOSED: vt[col][BS] so attention can stage V like K.
__global__ __launch_bounds__(256) void gemm_qkv_kernel(
        const ushort* __restrict__ A, const ushort* __restrict__ Bt,
        const float* __restrict__ bq, const float* __restrict__ bk,
        const float* __restrict__ bv,
        ushort* __restrict__ qo, ushort* __restrict__ ko,
        ushort* __restrict__ vt) {
    __shared__ ushort sA[128 * 32];
    __shared__ ushort sB[128 * 32];

    const int tid  = threadIdx.x;
    const int lane = tid & 63;
    const int wave = tid >> 6;
    const int wr   = wave >> 1;
    const int wc   = wave & 1;
    const int fr   = lane & 15;
    const int fq   = lane >> 4;
    const int m0 = blockIdx.y * 128;
    const int n0 = blockIdx.x * 128;
    const int K  = DD;

    const int strow = tid >> 2;
    const int stg   = tid & 3;
    const int stgs  = stg ^ ((strow >> 1) & 3);

    f32x4 acc[4][4];
#pragma unroll
    for (int mi = 0; mi < 4; ++mi)
#pragma unroll
        for (int ni = 0; ni < 4; ++ni)
            acc[mi][ni] = (f32x4){0.0f, 0.0f, 0.0f, 0.0f};

    uint4 apre[2], bpre[2];
#pragma unroll
    for (int it = 0; it < 2; ++it) {
        apre[it] = *reinterpret_cast<const uint4*>(
            A + (size_t)(m0 + strow + it * 64) * K + stg * 8);
        bpre[it] = *reinterpret_cast<const uint4*>(
            Bt + (size_t)(n0 + strow + it * 64) * K + stg * 8);
    }

    for (int k0 = 0; k0 < K; k0 += 32) {
#pragma unroll
        for (int it = 0; it < 2; ++it) {
            *reinterpret_cast<uint4*>(&sA[(strow + it * 64) * 32 + stgs * 8]) = apre[it];
            *reinterpret_cast<uint4*>(&sB[(strow + it * 64) * 32 + stgs * 8]) = bpre[it];
        }
        __syncthreads();
        if (k0 + 32 < K) {
#pragma unroll
            for (int it = 0; it < 2; ++it) {
                apre[it] = *reinterpret_cast<const uint4*>(
                    A + (size_t)(m0 + strow + it * 64) * K + k0 + 32 + stg * 8);
                bpre[it] = *reinterpret_cast<const uint4*>(
                    Bt + (size_t)(n0 + strow + it * 64) * K + k0 + 32 + stg * 8);
            }
        }

        bf16x8 af[4], bfr[4];
#pragma unroll
        for (int mi = 0; mi < 4; ++mi) {
            const int row = wr * 64 + mi * 16 + fr;
            const int gs  = fq ^ ((row >> 1) & 3);
            af[mi] = *reinterpret_cast<const bf16x8*>(&sA[row * 32 + gs * 8]);
        }
#pragma unroll
        for (int ni = 0; ni < 4; ++ni) {
            const int row = wc * 64 + ni * 16 + fr;
            const int gs  = fq ^ ((row >> 1) & 3);
            bfr[ni] = *reinterpret_cast<const bf16x8*>(&sB[row * 32 + gs * 8]);
        }
#pragma unroll
        for (int mi = 0; mi < 4; ++mi)
#pragma unroll
            for (int ni = 0; ni < 4; ++ni)
                acc[mi][ni] = __builtin_amdgcn_mfma_f32_16x16x32_bf16(
                    af[mi], bfr[ni], acc[mi][ni], 0, 0, 0);
        __syncthreads();
    }

    const int which = n0 >> 9;   // 0=q, 1=k, 2=v (block fully inside one range)
    if (which < 2) {
        ushort* out = which ? ko : qo;
        const float* bias = which ? bk : bq;
#pragma unroll
        for (int ni = 0; ni < 4; ++ni) {
            const int col = (n0 + wc * 64 + ni * 16 + fr) & 511;
            const float bvv = bias[col];
#pragma unroll
            for (int mi = 0; mi < 4; ++mi)
#pragma unroll
                for (int r = 0; r < 4; ++r) {
                    const int row = m0 + wr * 64 + mi * 16 + fq * 4 + r;
                    out[(size_t)row * QN + col] = f2bf(acc[mi][ni][r] + bvv);
                }
        }
    } else {
#pragma unroll
        for (int ni = 0; ni < 4; ++ni) {
            const int col = (n0 + wc * 64 + ni * 16 + fr) & 511;
            const float bvv = bv[col];
#pragma unroll
            for (int mi = 0; mi < 4; ++mi) {
                const int row_base = m0 + wr * 64 + mi * 16 + fq * 4;
                ushort4 pk = make_ushort4(
                    f2bf(acc[mi][ni][0] + bvv), f2bf(acc[mi][ni][1] + bvv),
                    f2bf(acc[mi][ni][2] + bvv), f2bf(acc[mi][ni][3] + bvv));
                *reinterpret_cast<ushort4*>(vt + (size_t)col * BS + row_base) = pk;
            }
        }
    }
}

// ---------------- GEMM + residual + LayerNorm fused ----------------
// A[BS][K] bf16, Bt[256][K] bf16 -> delta = A.Bt^T + bias;
// h = LN(h + delta) in place; hb = bf16(h).  64-row tile, full N=256/block;
// wave w owns rows w*16..+15 so LN row-reduce stays in-wave (shfl over 16 lanes).
__global__ __launch_bounds__(256) void gemm_ln_kernel(
        const ushort* __restrict__ A, const ushort* __restrict__ Bt,
        const float* __restrict__ bias, float* __restrict__ h,
        ushort* __restrict__ hb, const float* __restrict__ sc,
        const float* __restrict__ bi, int K) {
    __shared__ ushort sA[64 * 32];
    __shared__ ushort sB[256 * 32];

    const int tid  = threadIdx.x;
    const int lane = tid & 63;
    const int w    = tid >> 6;
    const int lf   = lane & 15;
    const int fq   = lane >> 4;
    const int m0   = blockIdx.x * 64;

    const int strow = tid >> 2;   // 0..63
    const int stg   = tid & 3;
    const int stgs  = stg ^ ((strow >> 1) & 3);

    f32x4 acc[16];
#pragma unroll
    for (int ni = 0; ni < 16; ++ni) acc[ni] = (f32x4){0.f, 0.f, 0.f, 0.f};

    uint4 apre;
    uint4 bpre[4];
    apre = *reinterpret_cast<const uint4*>(A + (size_t)(m0 + strow) * K + stg * 8);
#pragma unroll
    for (int it = 0; it < 4; ++it)
        bpre[it] = *reinterpret_cast<const uint4*>(
            Bt + (size_t)(strow + it * 64) * K + stg * 8);

    for (int k0 = 0; k0 < K; k0 += 32) {
        *reinterpret_cast<uint4*>(&sA[strow * 32 + stgs * 8]) = apre;
#pragma unroll
        for (int it = 0; it < 4; ++it)
            *reinterpret_cast<uint4*>(&sB[(strow + it * 64) * 32 + stgs * 8]) = bpre[it];
        __syncthreads();
        if (k0 + 32 < K) {
            apre = *reinterpret_cast<const uint4*>(
                A + (size_t)(m0 + strow) * K + k0 + 32 + stg * 8);
#pragma unroll
            for (int it = 0; it < 4; ++it)
                bpre[it] = *reinterpret_cast<const uint4*>(
                    Bt + (size_t)(strow + it * 64) * K + k0 + 32 + stg * 8);
        }

        const int arow = w * 16 + lf;
        const bf16x8 af = *reinterpret_cast<const bf16x8*>(
            &sA[arow * 32 + ((fq ^ ((arow >> 1) & 3)) << 3)]);
#pragma unroll
        for (int ni = 0; ni < 16; ++ni) {
            const int brow = ni * 16 + lf;
            const bf16x8 bfr = *reinterpret_cast<const bf16x8*>(
                &sB[brow * 32 + ((fq ^ ((brow >> 1) & 3)) << 3)]);
            acc[ni] = __builtin_amdgcn_mfma_f32_16x16x32_bf16(af, bfr, acc[ni], 0, 0, 0);
        }
        __syncthreads();
    }

    // epilogue: rows w*16 + fq*4 + r; cols ni*16 + lf
#pragma unroll
    for (int r = 0; r < 4; ++r) {
        const int row = m0 + w * 16 + fq * 4 + r;
        float tmp[16];
        float sum = 0.0f;
#pragma unroll
        for (int ni = 0; ni < 16; ++ni) {
            const int col = ni * 16 + lf;
            float v = acc[ni][r] + bias[col] + h[(size_t)row * DD + col];
            tmp[ni] = v;
            sum += v;
        }
#pragma unroll
        for (int off = 1; off < 16; off <<= 1) sum += __shfl_xor(sum, off, 64);
        const float mean = sum * (1.0f / DD);
        float vs = 0.0f;
#pragma unroll
        for (int ni = 0; ni < 16; ++ni) {
            float d = tmp[ni] - mean;
            vs += d * d;
        }
#pragma unroll
        for (int off = 1; off < 16; off <<= 1) vs += __shfl_xor(vs, off, 64);
        const float inv = rsqrtf(vs * (1.0f / DD) + 1e-5f);
#pragma unroll
        for (int ni = 0; ni < 16; ++ni) {
            const int col = ni * 16 + lf;
            float res = (tmp[ni] - mean) * inv * sc[col] + bi[col];
            h[(size_t)row * DD + col] = res;
            hb[(size_t)row * DD + col] = f2bf(res);
        }
    }
}

// ---------------- flash attention (MFMA, bf16, V pre-transposed) ----------
// One block per (q-tile 64, head, batch); 4 waves, wave w owns q-rows w*16..+15.
// q,k: [BS][512] row-major; vt: [512][BS] (d-major) -> V staged like K.
// LDS (bf16, granule swizzle g^(row&7)): Qs,Ks [row][64]; Vt [d][kv]; Ps [q][kv].
// Reg-prefetch: next tile's K/V loaded during current tile's compute.
__global__ __launch_bounds__(256) void flash_attn_kernel(
        const ushort* __restrict__ q, const ushort* __restrict__ k,
        const ushort* __restrict__ vt, ushort* __restrict__ o) {
    const int qt  = blockIdx.x;
    const int hh  = blockIdx.y;
    const int b   = blockIdx.z;
    const int tid = threadIdx.x;
    const int l   = tid & 63;
    const int w   = tid >> 6;
    const int lf  = l & 15;
    const int lg  = l >> 4;

    __shared__ ushort Qs[64 * 64];
    __shared__ ushort Ks[64 * 64];
    __shared__ ushort Vt[64 * 64];   // [d][kv]
    __shared__ ushort Ps[64 * 64];   // [q][kv]

    const size_t qbase = ((size_t)(b * SS + qt * 64)) * QN + hh * HDIM;
    const ushort* vbase = vt + (size_t)(hh * HDIM) * BS + (size_t)b * SS;

    // stage Q (row-major, swizzled)
#pragma unroll
    for (int it = 0; it < 2; ++it) {
        int gi = tid + it * 256;
        int row = gi >> 3, g = gi & 7;
        uint4 val = *reinterpret_cast<const uint4*>(
            q + qbase + (size_t)row * QN + g * 8);
        *reinterpret_cast<uint4*>(&Qs[row * 64 + ((g ^ (row & 7)) << 3)]) = val;
    }

    // per-thread staging coords (same for K and Vt)
    const int srow[2] = { tid >> 3, (tid + 256) >> 3 };
    const int sg      = tid & 7;

    f32x4 o_acc[4];
    float m_i[4], l_i[4];
#pragma unroll
    for (int r = 0; r < 4; ++r) { m_i[r] = -3.0e38f; l_i[r] = 0.0f; }
#pragma unroll
    for (int ni = 0; ni < 4; ++ni) o_acc[ni] = (f32x4){0.f, 0.f, 0.f, 0.f};

    uint4 kreg[2], vreg[2];
    {
        const size_t kbase = ((size_t)(b * SS)) * QN + hh * HDIM;   // kt = 0
#pragma unroll
        for (int it = 0; it < 2; ++it) {
            kreg[it] = *reinterpret_cast<const uint4*>(
                k + kbase + (size_t)srow[it] * QN + sg * 8);
            vreg[it] = *reinterpret_cast<const uint4*>(
                vbase + (size_t)srow[it] * BS + sg * 8);
        }
    }

    for (int kt = 0; kt <= qt; ++kt) {
        // LDS write from prefetch regs
#pragma unroll
        for (int it = 0; it < 2; ++it) {
            *reinterpret_cast<uint4*>(
                &Ks[srow[it] * 64 + ((sg ^ (srow[it] & 7)) << 3)]) = kreg[it];
            *reinterpret_cast<uint4*>(
                &Vt[srow[it] * 64 + ((sg ^ (srow[it] & 7)) << 3)]) = vreg[it];
        }
        __syncthreads();

        if (kt < qt) {
            const size_t kbase = ((size_t)(b * SS + (kt + 1) * 64)) * QN + hh * HDIM;
#pragma unroll
            for (int it = 0; it < 2; ++it) {
                kreg[it] = *reinterpret_cast<const uint4*>(
                    k + kbase + (size_t)srow[it] * QN + sg * 8);
                vreg[it] = *reinterpret_cast<const uint4*>(
                    vbase + (kt + 1) * 64 + (size_t)srow[it] * BS + sg * 8);
            }
        }

        // ---- S = Q . K^T (per wave: 16q x 64kv) ----
        f32x4 st[4];
#pragma unroll
        for (int ni = 0; ni < 4; ++ni) st[ni] = (f32x4){0.f, 0.f, 0.f, 0.f};
        const int arow = w * 16 + lf;
#pragma unroll
        for (int ks = 0; ks < 2; ++ks) {
            bf16x8 aq = *reinterpret_cast<const bf16x8*>(
                &Qs[arow * 64 + (((ks * 4 + lg) ^ (arow & 7)) << 3)]);
#pragma unroll
            for (int ni = 0; ni < 4; ++ni) {
                const int brow = ni * 16 + lf;
                bf16x8 bk = *reinterpret_cast<const bf16x8*>(
                    &Ks[brow * 64 + (((ks * 4 + lg) ^ (brow & 7)) << 3)]);
                st[ni] = __builtin_amdgcn_mfma_f32_16x16x32_bf16(aq, bk, st[ni], 0, 0, 0);
            }
        }
#pragma unroll
        for (int ni = 0; ni < 4; ++ni) st[ni] *= 0.125f;

        // causal mask on diagonal tile
        if (kt == qt) {
#pragma unroll
            for (int ni = 0; ni < 4; ++ni)
#pragma unroll
                for (int r = 0; r < 4; ++r)
                    if (16 * ni + lf > w * 16 + 4 * lg + r) st[ni][r] = -1.0e30f;
        }

        // ---- online softmax (lane owns q-rows w*16+4*lg+r, kv cols lf+16ni) --
#pragma unroll
        for (int r = 0; r < 4; ++r) {
            float mx = fmaxf(fmaxf(st[0][r], st[1][r]), fmaxf(st[2][r], st[3][r]));
#pragma unroll
            for (int off = 1; off < 16; off <<= 1)
                mx = fmaxf(mx, __shfl_xor(mx, off, 64));
            float mnew = fmaxf(m_i[r], mx);
            float alpha = __expf(m_i[r] - mnew);
            float sum = 0.0f;
#pragma unroll
            for (int ni = 0; ni < 4; ++ni) {
                float p = __expf(st[ni][r] - mnew);
                st[ni][r] = p;
                sum += p;
            }
#pragma unroll
            for (int off = 1; off < 16; off <<= 1)
                sum += __shfl_xor(sum, off, 64);
            m_i[r] = mnew;
            l_i[r] = l_i[r] * alpha + sum;
#pragma unroll
            for (int ni = 0; ni < 4; ++ni) o_acc[ni][r] *= alpha;
        }

        // ---- P -> LDS (bf16, wave-private rows; swizzled) ----
#pragma unroll
        for (int r = 0; r < 4; ++r) {
            const int qr = w * 16 + 4 * lg + r;
#pragma unroll
            for (int ni = 0; ni < 4; ++ni) {
                const int kvc = 16 * ni + lf;
                Ps[qr * 64 + (((kvc >> 3) ^ (qr & 7)) << 3) + (kvc & 7)] =
                    f2bf(st[ni][r]);
            }
        }
        asm volatile("s_waitcnt lgkmcnt(0)" ::: "memory");
        __builtin_amdgcn_sched_barrier(0);

        // ---- O += P . V  (B rows = Vt[d][kv]) ----
#pragma unroll
        for (int ks = 0; ks < 2; ++ks) {
            bf16x8 pa = *reinterpret_cast<const bf16x8*>(
                &Ps[arow * 64 + (((ks * 4 + lg) ^ (arow & 7)) << 3)]);
#pragma unroll
            for (int ni = 0; ni < 4; ++ni) {
                const int drow = ni * 16 + lf;
                bf16x8 vb = *reinterpret_cast<const bf16x8*>(
                    &Vt[drow * 64 + (((ks * 4 + lg) ^ (drow & 7)) << 3)]);
                o_acc[ni] = __builtin_amdgcn_mfma_f32_16x16x32_bf16(pa, vb, o_acc[ni], 0, 0, 0);
            }
        }
        __syncthreads();   // all reads of Ks/Vt done before next-tile LDS write
    }

    // ---- write O (bf16) ----
#pragma unroll
    for (int r = 0; r < 4; ++r) {
        const float invl = 1.0f / l_i[r];
        const int qrow = w * 16 + 4 * lg + r;
#pragma unroll
        for (int ni = 0; ni < 4; ++ni)
            o[qbase + (size_t)qrow * QN + 16 * ni + lf] =
                f2bf(o_acc[ni][r] * invl);
    }
}

// ---------------- launch ----------------
extern "C" void kernel_launch(void* const* d_in, const int* in_sizes, int n_in,
                              void* d_out, int out_size, void* d_ws, size_t ws_size,
                              hipStream_t stream) {
    (void)in_sizes; (void)n_in; (void)out_size; (void)ws_size;

    const int*   x    = (const int*)d_in[0];
    const float* emb  = (const float*)d_in[1];
    const float* wq   = (const float*)d_in[2];
    const float* bq   = (const float*)d_in[3];
    const float* wk   = (const float*)d_in[4];
    const float* bk   = (const float*)d_in[5];
    const float* wv   = (const float*)d_in[6];
    const float* bv   = (const float*)d_in[7];
    const float* wo   = (const float*)d_in[8];
    const float* bo   = (const float*)d_in[9];
    const float* ln1s = (const float*)d_in[10];
    const float* ln1b = (const float*)d_in[11];
    const float* w1   = (const float*)d_in[12];
    const float* b1   = (const float*)d_in[13];
    const float* w2   = (const float*)d_in[14];
    const float* b2   = (const float*)d_in[15];
    const float* ln2s = (const float*)d_in[16];
    const float* ln2b = (const float*)d_in[17];
    const float* ow   = (const float*)d_in[18];
    const float* ob   = (const float*)d_in[19];

    // workspace layout (~88 MB)
    char* ws = (char*)d_ws;
    float*  h     = (float*)ws;   ws += (size_t)BS * DD * 4;
    ushort* hbf   = (ushort*)ws;  ws += (size_t)BS * DD * 2;
    ushort* qb    = (ushort*)ws;  ws += (size_t)BS * QN * 2;
    ushort* kb    = (ushort*)ws;  ws += (size_t)BS * QN * 2;
    ushort* vbt   = (ushort*)ws;  ws += (size_t)QN * BS * 2;   // transposed V
    ushort* wqkvt = (ushort*)ws;  ws += (size_t)NLAYER * 3 * QN * DD * 2;
    ushort* wot   = (ushort*)ws;  ws += (size_t)NLAYER * DD * QN * 2;
    ushort* w1t   = (ushort*)ws;  ws += (size_t)NLAYER * FFD * DD * 2;
    ushort* w2t   = (ushort*)ws;  ws += (size_t)NLAYER * DD * FFD * 2;
    ushort* owt   = (ushort*)ws;  ws += (size_t)OUTD * DD * 2;
    ushort* ao    = qb;           // attention out aliases q
    ushort* ffh   = kb;           // FFN hidden aliases k+v (33.6 MB)

    // weight conversion (f32 [K][N] -> bf16 [N][K]); qkv concatenated
    for (int i = 0; i < NLAYER; ++i) {
        ushort* base = wqkvt + (size_t)i * 3 * QN * DD;
        convw_kernel<<<dim3(QN / 32, DD / 32), 256, 0, stream>>>(
            wq + (size_t)i * DD * QN, base, DD, QN);
        convw_kernel<<<dim3(QN / 32, DD / 32), 256, 0, stream>>>(
            wk + (size_t)i * DD * QN, base + (size_t)QN * DD, DD, QN);
        convw_kernel<<<dim3(QN / 32, DD / 32), 256, 0, stream>>>(
            wv + (size_t)i * DD * QN, base + (size_t)2 * QN * DD, DD, QN);
        convw_kernel<<<dim3(DD / 32, QN / 32), 256, 0, stream>>>(
            wo + (size_t)i * QN * DD, wot + (size_t)i * DD * QN, QN, DD);
        convw_kernel<<<dim3(FFD / 32, DD / 32), 256, 0, stream>>>(
            w1 + (size_t)i * DD * FFD, w1t + (size_t)i * FFD * DD, DD, FFD);
        convw_kernel<<<dim3(DD / 32, FFD / 32), 256, 0, stream>>>(
            w2 + (size_t)i * FFD * DD, w2t + (size_t)i * DD * FFD, FFD, DD);
    }
    convw_kernel<<<dim3(OUTD / 32, DD / 32), 256, 0, stream>>>(ow, owt, DD, OUTD);

    embed_pe_kernel<<<BS, 256, 0, stream>>>(x, emb, h, hbf);

    for (int i = 0; i < NLAYER; ++i) {
        gemm_qkv_kernel<<<dim3(12, BS / 128), 256, 0, stream>>>(
            hbf, wqkvt + (size_t)i * 3 * QN * DD,
            bq + i * QN, bk + i * QN, bv + i * QN, qb, kb, vbt);

        flash_attn_kernel<<<dim3(SS / 64, HH, BB), 256, 0, stream>>>(qb, kb, vbt, ao);

        gemm_ln_kernel<<<BS / 64, 256, 0, stream>>>(
            ao, wot + (size_t)i * DD * QN, bo + i * DD, h, hbf,
            ln1s + i * DD, ln1b + i * DD, QN);

        gemm_mfma_kernel<true, true><<<dim3(FFD / 128, BS / 128), 256, 0, stream>>>(
            hbf, w1t + (size_t)i * FFD * DD, b1 + i * FFD, ffh, BS, FFD, DD);

        gemm_ln_kernel<<<BS / 64, 256, 0, stream>>>(
            ffh, w2t + (size_t)i * DD * FFD, b2 + i * DD, h, hbf,
            ln2s + i * DD, ln2b + i * DD, FFD);
    }

    gemm_mfma_kernel<false, false><<<dim3(OUTD / 128, BS / 128), 256, 0, stream>>>(
        hbf, owt, ob, (float*)d_out, BS, OUTD, DD);
}